// Round 3
// 3460.677 us; speedup vs baseline: 1.0124x; 1.0124x over previous
//
#include <hip/hip_runtime.h>

typedef unsigned short u16;
typedef unsigned int   u32;
typedef unsigned long long u64;
typedef __attribute__((ext_vector_type(8))) short short8;    // 8 x bf16 operand (4 VGPRs)
typedef __attribute__((ext_vector_type(4))) float f32x4;     // 16x16 MFMA accumulator
typedef __attribute__((ext_vector_type(16))) float f32x16;   // 32x32 MFMA accumulator

// ---------------- workspace layout (bytes) — round-0 proven ----------------
// G1    : [512 t][128 w][4 gate][8 u][32 b] bf16 = 134217728  (block-local 2 KB slabs)
// h1ring: 4 ring buffers, 32x32-A-frag layout (chunk = kb*32+b, 16 B), 64 KiB each
// h2buf : 2 parity buffers, same layout
// h2f   : final h2 [32][1024] fp32
// cnt   : cnt0 = 8 counters at u32 idx i*32 (L0), cnt1 = 8 at 1024+i*32 (L1); 8 KiB
#define OFF_H1   134217728ull
#define OFF_H2   (OFF_H1 + 262144ull)
#define OFF_H2F  (OFF_H2 + 131072ull)
#define OFF_CNT  (OFF_H2F + 131072ull)

__device__ inline u16 f2bf(float f) {                  // fp32 -> bf16 RNE
  u32 x = __float_as_uint(f);
  x += 0x7fffu + ((x >> 16) & 1u);
  return (u16)(x >> 16);
}
__device__ inline float bf2f(u16 u) { return __uint_as_float(((u32)u) << 16); }

__device__ inline short8 pack_bf16x8(float4 a, float4 b) {
  short8 r;
  r[0] = (short)f2bf(a.x); r[1] = (short)f2bf(a.y); r[2] = (short)f2bf(a.z); r[3] = (short)f2bf(a.w);
  r[4] = (short)f2bf(b.x); r[5] = (short)f2bf(b.y); r[6] = (short)f2bf(b.z); r[7] = (short)f2bf(b.w);
  return r;
}

__device__ inline f32x16 mfma32(short8 a, short8 b, f32x16 c) {
  return __builtin_amdgcn_mfma_f32_32x32x16_bf16(a, b, c, 0, 0, 0);
}

__device__ inline float sigf(float x) { return 1.f / (1.f + __expf(-x)); }
__device__ inline float tanhfast(float x) {
  x = fminf(15.f, fmaxf(-15.f, x));
  float e = __expf(2.f * x);
  return (e - 1.f) / (e + 1.f);
}

// 8 coherent (LLC-direct) 16-B loads, pipelined, drained inside the asm.
// "=&v" early-clobber: outputs must not alias address inputs.
__device__ inline void load8_frags(const char* a0, uint4 f[8]) {
  const char* a1 = a0 + 4096;
  asm volatile(
    "global_load_dwordx4 %0, %8, off sc0 sc1\n\t"
    "global_load_dwordx4 %1, %8, off offset:1024 sc0 sc1\n\t"
    "global_load_dwordx4 %2, %8, off offset:2048 sc0 sc1\n\t"
    "global_load_dwordx4 %3, %8, off offset:3072 sc0 sc1\n\t"
    "global_load_dwordx4 %4, %9, off sc0 sc1\n\t"
    "global_load_dwordx4 %5, %9, off offset:1024 sc0 sc1\n\t"
    "global_load_dwordx4 %6, %9, off offset:2048 sc0 sc1\n\t"
    "global_load_dwordx4 %7, %9, off offset:3072 sc0 sc1\n\t"
    "s_waitcnt vmcnt(0)"
    : "=&v"(f[0]), "=&v"(f[1]), "=&v"(f[2]), "=&v"(f[3]),
      "=&v"(f[4]), "=&v"(f[5]), "=&v"(f[6]), "=&v"(f[7])
    : "v"(a0), "v"(a1));
}

// Same 8-load flight but ISSUE ONLY (no drain): used to overlap load service
// time with a subsequent counter-poll. Consumption must follow an explicit
// s_waitcnt vmcnt(0) + sched_barrier(0) (guide rule #18).
__device__ inline void load8_issue(const char* a0, uint4 f[8]) {
  const char* a1 = a0 + 4096;
  asm volatile(
    "global_load_dwordx4 %0, %8, off sc0 sc1\n\t"
    "global_load_dwordx4 %1, %8, off offset:1024 sc0 sc1\n\t"
    "global_load_dwordx4 %2, %8, off offset:2048 sc0 sc1\n\t"
    "global_load_dwordx4 %3, %8, off offset:3072 sc0 sc1\n\t"
    "global_load_dwordx4 %4, %9, off sc0 sc1\n\t"
    "global_load_dwordx4 %5, %9, off offset:1024 sc0 sc1\n\t"
    "global_load_dwordx4 %6, %9, off offset:2048 sc0 sc1\n\t"
    "global_load_dwordx4 %7, %9, off offset:3072 sc0 sc1"
    : "=&v"(f[0]), "=&v"(f[1]), "=&v"(f[2]), "=&v"(f[3]),
      "=&v"(f[4]), "=&v"(f[5]), "=&v"(f[6]), "=&v"(f[7])
    : "v"(a0), "v"(a1)
    : "memory");
}

// ---------------- init: zero h ring+h2 buffers + barrier counters ----------------
__global__ void init_zero_k(uint4* __restrict__ z, int n4, u32* __restrict__ cnt) {
  const int i = blockIdx.x * blockDim.x + threadIdx.x;
  if (i < n4)   z[i] = make_uint4(0u, 0u, 0u, 0u);
  if (i < 2048) cnt[i] = 0u;
}

// ---------------- phase A: G1 = emb[x] @ Wih1^T (bf16 MFMA), relayout epilogue ----
__global__ __launch_bounds__(256) void gemm_g1(
    const int* __restrict__ x, const float* __restrict__ emb,
    const float* __restrict__ Wih, u16* __restrict__ G1)
{
  __shared__ __align__(16) u16 lsbuf[2 * 128 * 72];   // 36864 B, aliased below
  __shared__ int tokoff[128];
  u16* lA = lsbuf;               // [128*72]
  u16* lB = lsbuf + 128 * 72;    // [128*72]
  u16* ltile = lsbuf;            // [128*136], reused after K-loop

  const int tid = threadIdx.x;
  const int ntb = blockIdx.x & 31;     // N tile (gate rows)
  const int mtb = blockIdx.x >> 5;     // M tile (time*batch rows)

  if (tid < 128) {
    const int n = mtb * 128 + tid;
    tokoff[tid] = x[(n & 31) * 512 + (n >> 5)];   // x[b][t], b=n&31, t=n>>5
  }
  __syncthreads();

  const int lane = tid & 63;
  const int wv = tid >> 6;
  const int wm = (wv & 1) * 64;
  const int wn = (wv >> 1) * 64;

  const f32x4 zero = {0.f, 0.f, 0.f, 0.f};
  f32x4 acc[4][4];
#pragma unroll
  for (int i = 0; i < 4; ++i)
#pragma unroll
    for (int j = 0; j < 4; ++j) acc[i][j] = zero;

  const int rowS = tid >> 1;
  const int kh = (tid & 1) * 32;
  const size_t embrow = (size_t)tokoff[rowS] * 1024;
  const size_t wihrow = (size_t)(ntb * 128 + rowS) * 1024;

  for (int kk = 0; kk < 1024; kk += 64) {
    __syncthreads();
    {
      const float4* sa = (const float4*)(emb + embrow + kk + kh);
      const float4* sb = (const float4*)(Wih + wihrow + kk + kh);
#pragma unroll
      for (int v = 0; v < 4; ++v) {
        *(short8*)&lA[rowS * 72 + kh + v * 8] = pack_bf16x8(sa[2 * v], sa[2 * v + 1]);
        *(short8*)&lB[rowS * 72 + kh + v * 8] = pack_bf16x8(sb[2 * v], sb[2 * v + 1]);
      }
    }
    __syncthreads();
#pragma unroll
    for (int ks = 0; ks < 2; ++ks) {
      short8 aF[4], bF[4];
#pragma unroll
      for (int i = 0; i < 4; ++i)
        aF[i] = *(const short8*)&lA[(wm + i * 16 + (lane & 15)) * 72 + ks * 32 + (lane >> 4) * 8];
#pragma unroll
      for (int i = 0; i < 4; ++i)
        bF[i] = *(const short8*)&lB[(wn + i * 16 + (lane & 15)) * 72 + ks * 32 + (lane >> 4) * 8];
#pragma unroll
      for (int i = 0; i < 4; ++i)
#pragma unroll
        for (int j = 0; j < 4; ++j)
          acc[i][j] = __builtin_amdgcn_mfma_f32_16x16x32_bf16(aF[i], bF[j], acc[i][j], 0, 0, 0);
    }
  }
  __syncthreads();   // done reading lA/lB before ltile overlay writes

#pragma unroll
  for (int i = 0; i < 4; ++i)
#pragma unroll
    for (int j = 0; j < 4; ++j)
#pragma unroll
      for (int r = 0; r < 4; ++r)
        ltile[(wm + i * 16 + (lane >> 4) * 4 + r) * 136 + wn + j * 16 + (lane & 15)] =
            f2bf(acc[i][j][r]);
  __syncthreads();

  const int gate = ntb >> 3;
  const int w0 = (ntb & 7) * 16;
  const int chunkid = tid >> 2;      // 0..63  (tloc 0..3 x wloc 0..15)
  const int part = tid & 3;          // quarter of a 512-B chunk
  const int tloc = chunkid >> 4;
  const int wloc = chunkid & 15;
  const size_t base =
      ((size_t)((mtb * 4 + tloc) * 128 + w0 + wloc) * 4 + gate) * 256;
#pragma unroll
  for (int m = 0; m < 8; ++m) {
    const int idx = part * 64 + m * 8;     // u*32 + b0
    const int u = idx >> 5;
    const int b0 = idx & 31;
    union { u16 h[8]; uint4 q; } t;
#pragma unroll
    for (int k = 0; k < 8; ++k)
      t.h[k] = ltile[(tloc * 32 + b0 + k) * 136 + wloc * 8 + u];
    *(uint4*)(G1 + base + idx) = t.q;
  }
}

// ---------------- split grid wait: sum(cnt0) >= t0 && sum(cnt1) >= t1 ----------------
__device__ inline void gwait(u32* cnt, int t0, int t1) {
  if (threadIdx.x < 64 && (t0 > 0 || t1 > 0)) {
    int guard = 0;
    for (;;) {
      int v = 0;
      if (threadIdx.x < 8)
        v = (int)__hip_atomic_load(cnt + threadIdx.x * 32,
                                   __ATOMIC_RELAXED, __HIP_MEMORY_SCOPE_AGENT);
      else if (threadIdx.x < 16)
        v = (int)__hip_atomic_load(cnt + 1024 + (threadIdx.x - 8) * 32,
                                   __ATOMIC_RELAXED, __HIP_MEMORY_SCOPE_AGENT);
      v += __shfl_xor(v, 1);
      v += __shfl_xor(v, 2);
      v += __shfl_xor(v, 4);
      const int s0 = __shfl(v, 0);
      const int s1 = __shfl(v, 8);
      if (s0 >= t0 && s1 >= t1) break;
      if (++guard > (1 << 20)) break;   // hang insurance
      __builtin_amdgcn_s_sleep(1);
    }
  }
  __syncthreads();
  asm volatile("" ::: "memory");
}

// ---------------- single-counter wait: sum over 8 lines at cbase >= t ----------------
__device__ inline void gwait8(u32* cbase, int t) {
  if (threadIdx.x < 64 && t > 0) {
    int guard = 0;
    for (;;) {
      int v = 0;
      if (threadIdx.x < 8)
        v = (int)__hip_atomic_load(cbase + threadIdx.x * 32,
                                   __ATOMIC_RELAXED, __HIP_MEMORY_SCOPE_AGENT);
      v += __shfl_xor(v, 1);
      v += __shfl_xor(v, 2);
      v += __shfl_xor(v, 4);
      if (__shfl(v, 0) >= t) break;
      if (++guard > (1 << 20)) break;   // hang insurance
      __builtin_amdgcn_s_sleep(1);
    }
  }
  __syncthreads();
  asm volatile("" ::: "memory");
}

// ---------------- persistent fused 2-layer LSTM, decoupled layer pipelines ----------
// 256 blocks x 512 threads (1 block/CU, 8 waves, (512,2) -> 256-VGPR cap).
// Block w of layer l owns hidden units w*8..w*8+7. 8 waves split K: wave wv does
// K in [wv*128,+128) of every matrix it touches.
//   L0: Whh1 slice in VGPR (8 frags). Reads h1ring[(s-1)%4], writes h1ring[s%4].
//       Waits: cnt0 >= 128*s (h1[s-1] ready), cnt1 >= 128*(s-3) (ring overwrite guard).
//   L1: Wih2 + Whh2 slices in VGPR (8+8 frags). SPLIT WAIT (this round's change):
//       wait cnt1 >= 128*s  -> issue 8 h2 loads (no drain)
//       wait cnt0 >= 128*(s+1) -> issue 8 h1 loads -> one drain -> MFMA.
//       The h2 load service time hides under the cnt0 poll. Same read-entry
//       conditions as round-0's combined gwait, so all overwrite invariants hold.
__global__ __launch_bounds__(512, 2) void lstm_recur(
    const float* __restrict__ Wih_all, const float* __restrict__ Whh_all,
    const float* __restrict__ bias_all, const u16* __restrict__ G1,
    u64* __restrict__ h1ring, u64* __restrict__ h2buf,
    float* __restrict__ h2f, u32* __restrict__ cnt)
{
  __shared__ float gp[8][32][33];                // per-wave partial gates (33.8 KB)
  __shared__ __align__(16) u16 hpack[32 * 8];    // [b][u] bf16 staging

  const int tid = threadIdx.x;
  const int lane = tid & 63;
  const int wv = tid >> 6;          // 0..7
  const int bid = blockIdx.x;
  const int layer = bid >> 7;
  const int w = bid & 127;

  const int pu = (tid >> 5) & 7;    // pointwise: unit
  const int pb = tid & 31;          // pointwise: batch
  const bool pw_act = tid < 256;
  float creg = 0.f;
  float bs0 = 0.f, bs1 = 0.f, bs2 = 0.f, bs3 = 0.f;
  if (pw_act) {
    const float* bb = bias_all + layer * 4096 + w * 8 + pu;
    bs0 = bb[0]; bs1 = bb[1024]; bs2 = bb[2048]; bs3 = bb[3072];
  }

  // ---- weight B-fragments, VGPR-resident ----
  const int nA = lane & 31;
  const int kpart = (lane >> 5) * 8;
  const size_t wrow = (size_t)((nA >> 3) * 1024 + w * 8 + (nA & 7)) * 1024;
  const int K0 = wv * 128;
  short8 bw0[8], bw1[8];   // L0: bw0=Whh1 (bw1 unused); L1: bw0=Wih2, bw1=Whh2
  {
    const float* s0 = (layer == 0) ? Whh_all : (Wih_all + 4194304);
#pragma unroll
    for (int ks = 0; ks < 8; ++ks) {
      const float* p = s0 + wrow + (K0 + ks * 16 + kpart);
      bw0[ks] = pack_bf16x8(((const float4*)p)[0], ((const float4*)p)[1]);
    }
    if (layer == 1) {
      const float* s1 = Whh_all + 4194304;
#pragma unroll
      for (int ks = 0; ks < 8; ++ks) {
        const float* p = s1 + wrow + (K0 + ks * 16 + kpart);
        bw1[ks] = pack_bf16x8(((const float4*)p)[0], ((const float4*)p)[1]);
      }
    }
  }

  // per-lane A byte offset within one 64 KiB buffer
  const int aoff = ((wv * 16 + (lane >> 5)) * 32 + (lane & 31)) * 16;

  // prefetch step-0 input-projection gates (layer 0)
  float g0 = 0.f, g1v = 0.f, g2 = 0.f, g3 = 0.f;
  if (layer == 0 && pw_act) {
    const u16* gpt = G1 + (size_t)w * 1024 + pu * 32 + pb;   // t=0
    g0 = bf2f(gpt[0]); g1v = bf2f(gpt[256]); g2 = bf2f(gpt[512]); g3 = bf2f(gpt[768]);
  }

  for (int s = 0; s < 512; ++s) {
    f32x16 accA = {0.f,0.f,0.f,0.f,0.f,0.f,0.f,0.f,0.f,0.f,0.f,0.f,0.f,0.f,0.f,0.f};
    if (layer == 0) {
      gwait(cnt, 128 * s, 128 * (s - 3));
      const char* a0 = (const char*)h1ring + (size_t)((s + 3) & 3) * 65536 + aoff;
      uint4 f[8];
      load8_frags(a0, f);
#pragma unroll
      for (int i = 0; i < 8; ++i)
        accA = mfma32(__builtin_bit_cast(short8, f[i]), bw0[i], accA);
    } else {
      // ---- split wait + load overlap (round-0 thresholds preserved) ----
      gwait8(cnt + 1024, 128 * s);                 // h2[s-1] posted by all L1
      const char* aH = (const char*)h2buf + (size_t)((s + 1) & 1) * 65536 + aoff;
      uint4 fH[8];
      load8_issue(aH, fH);                          // in flight during cnt0 poll
      gwait8(cnt, 128 * (s + 1));                   // h1[s] posted by all L0
      const char* aI = (const char*)h1ring + (size_t)(s & 3) * 65536 + aoff;
      uint4 fI[8];
      load8_issue(aI, fI);
      asm volatile("s_waitcnt vmcnt(0)" ::: "memory");
      __builtin_amdgcn_sched_barrier(0);            // no MFMA hoisting past drain
      f32x16 accB = {0.f,0.f,0.f,0.f,0.f,0.f,0.f,0.f,0.f,0.f,0.f,0.f,0.f,0.f,0.f,0.f};
#pragma unroll
      for (int i = 0; i < 8; ++i)
        accA = mfma32(__builtin_bit_cast(short8, fI[i]), bw0[i], accA);
#pragma unroll
      for (int i = 0; i < 8; ++i)
        accB = mfma32(__builtin_bit_cast(short8, fH[i]), bw1[i], accB);
      accA += accB;
    }
    // 32x32 C/D layout: col = lane&31, row = (r&3) + 8*(r>>2) + 4*(lane>>5)
#pragma unroll
    for (int r = 0; r < 16; ++r)
      gp[wv][(r & 3) + 8 * (r >> 2) + 4 * (lane >> 5)][lane & 31] = accA[r];
    __syncthreads();
    if (pw_act) {
      float gi = bs0 + g0, gf = bs1 + g1v, gg = bs2 + g2, go = bs3 + g3;
#pragma unroll
      for (int q = 0; q < 8; ++q) {
        gi += gp[q][pb][pu];
        gf += gp[q][pb][8 + pu];
        gg += gp[q][pb][16 + pu];
        go += gp[q][pb][24 + pu];
      }
      creg = sigf(gf) * creg + sigf(gi) * tanhfast(gg);
      const float hval = sigf(go) * tanhfast(creg);
      hpack[pb * 8 + pu] = f2bf(hval);
      if (layer == 1 && s == 511) h2f[pb * 1024 + w * 8 + pu] = hval;
    }
    __syncthreads();
    if (tid < 32) {
      const u64* hp = (const u64*)(hpack + tid * 8);
      const u64 lo = hp[0], hi = hp[1];
      u64* dst = (layer == 0) ? (h1ring + (size_t)(s & 3) * 8192)
                              : (h2buf + (size_t)(s & 1) * 8192);
      const int chunk = w * 32 + tid;
      __hip_atomic_store(dst + chunk * 2,     lo, __ATOMIC_RELAXED, __HIP_MEMORY_SCOPE_AGENT);
      __hip_atomic_store(dst + chunk * 2 + 1, hi, __ATOMIC_RELAXED, __HIP_MEMORY_SCOPE_AGENT);
    }
    if (wv == 0) {
      __builtin_amdgcn_s_waitcnt(0);    // drain h stores to the coherence point
      if (tid == 0)
        __hip_atomic_fetch_add(cnt + (layer == 0 ? 0 : 1024) + ((bid & 7) << 5), 1u,
                               __ATOMIC_RELAXED, __HIP_MEMORY_SCOPE_AGENT);
    }
    // prefetch next step's G1 gates (layer 0) — after the post so its HBM
    // latency doesn't sit on the signal path
    if (layer == 0 && pw_act && s + 1 < 512) {
      const u16* gpt = G1 + ((size_t)(s + 1) * 128 + w) * 1024 + pu * 32 + pb;
      g0 = bf2f(gpt[0]); g1v = bf2f(gpt[256]); g2 = bf2f(gpt[512]); g3 = bf2f(gpt[768]);
    }
  }
}

// ---------------- epilogue: logits, log-softmax, NLL ----------------
__global__ __launch_bounds__(256) void epilogue_k(
    const float* __restrict__ h2f, const float* __restrict__ fcW,
    const float* __restrict__ fcb, const int* __restrict__ labels,
    float* __restrict__ out)
{
  __shared__ float slog[160];
  __shared__ float snll[32];
  const int tid = threadIdx.x;
  const int lane = tid & 63;
  const int wv = tid >> 6;
  for (int d = wv * 40; d < (wv + 1) * 40; ++d) {
    const int b = d / 5, l = d - b * 5;
    const float* hr = h2f + b * 1024 + lane * 16;
    const float* wr = fcW + l * 1024 + lane * 16;
    float sacc = 0.f;
#pragma unroll
    for (int i = 0; i < 16; ++i) sacc += hr[i] * wr[i];
#pragma unroll
    for (int off = 32; off > 0; off >>= 1) sacc += __shfl_down(sacc, off);
    if (lane == 0) slog[d] = sacc + fcb[l];
  }
  __syncthreads();
  if (tid < 32) {
    const int b = tid;
    float m = slog[b * 5];
    for (int l = 1; l < 5; ++l) m = fmaxf(m, slog[b * 5 + l]);
    float se = 0.f;
    for (int l = 0; l < 5; ++l) se += __expf(slog[b * 5 + l] - m);
    const float lse = m + __logf(se);
    for (int l = 0; l < 5; ++l) out[1 + b * 5 + l] = slog[b * 5 + l];
    snll[b] = lse - slog[b * 5 + labels[b]];
  }
  __syncthreads();
  if (tid == 0) {
    float a = 0.f;
    for (int b = 0; b < 32; ++b) a += snll[b];
    out[0] = a * (1.f / 32.f);
  }
}

extern "C" void kernel_launch(void* const* d_in, const int* in_sizes, int n_in,
                              void* d_out, int out_size, void* d_ws, size_t ws_size,
                              hipStream_t stream)
{
  const int*   x      = (const int*)  d_in[0];
  const int*   labels = (const int*)  d_in[1];
  const float* emb    = (const float*)d_in[2];
  const float* W_ih   = (const float*)d_in[3];
  const float* W_hh   = (const float*)d_in[4];
  const float* bias   = (const float*)d_in[5];
  const float* fcW    = (const float*)d_in[6];
  const float* fcb    = (const float*)d_in[7];
  float* out = (float*)d_out;

  char* ws = (char*)d_ws;
  u16* G1     = (u16*)ws;
  u64* h1ring = (u64*)(ws + OFF_H1);
  u64* h2buf  = (u64*)(ws + OFF_H2);
  float* h2f  = (float*)(ws + OFF_H2F);
  u32* cnt    = (u32*)(ws + OFF_CNT);

  // zero h1 ring + h2 buffers (393216 B = 24576 uint4) + barrier counters
  init_zero_k<<<dim3(96), dim3(256), 0, stream>>>((uint4*)(ws + OFF_H1), 24576, cnt);
  // phase A: all input projections for layer 1 (relayout epilogue)
  gemm_g1<<<dim3(4096), dim3(256), 0, stream>>>(x, emb, W_ih, G1);
  // persistent fused recurrence (1 block/CU, 512 threads, decoupled pipelines)
  lstm_recur<<<dim3(256), dim3(512), 0, stream>>>(W_ih, W_hh, bias, G1, h1ring, h2buf, h2f, cnt);
  // loss + logits
  epilogue_k<<<dim3(1), dim3(256), 0, stream>>>(h2f, fcW, fcb, labels, out);
}